// Round 1
// baseline (367.888 us; speedup 1.0000x reference)
//
#include <hip/hip_runtime.h>
#include <cfloat>

#define GT 16
#define NCLS 81
#define TPB 256
#define BPT 1024
#define MAXP 8732
#define TROWS 64
#define WF4 324              // float4 per wave slice: 16 rows * 81 / 4
#define TF4 (TROWS*NCLS/4)   // 1296 float4 per tile

__device__ __forceinline__ float smoothl1(float d){
  float a = fabsf(d);
  return a < 1.0f ? 0.5f*a*a : a - 0.5f;
}

// Kernel 1: per-(batch,gt) best prior via block-local reduction.
// One block per batch, 1024 threads; no global atomics, no poison
// dependency (overwrites all outputs). Fuses per-batch accumulator init.
__global__ __launch_bounds__(BPT) void bestprior(
    const float* __restrict__ priors,     // (P,4) xywh
    const float* __restrict__ gt_boxes,   // (B,GT,4) xyxy
    int*   __restrict__ best,             // (B,GT) prior index
    float* __restrict__ ce_pos, float* __restrict__ sl1_sum,
    int* __restrict__ num_pos, float* __restrict__ out, int P)
{
  const int b = blockIdx.x;
  const int tid = threadIdx.x, wave = tid >> 6, lane = tid & 63;
  __shared__ float gx0[GT], gy0[GT], gx1[GT], gy1[GT], ga[GT];
  __shared__ float redv[16*GT]; __shared__ int redi[16*GT];
  if (tid == 0){ ce_pos[b] = 0.0f; sl1_sum[b] = 0.0f; num_pos[b] = 0; }
  if (b == 0 && tid < 2) out[tid] = 0.0f;
  if (tid < GT){
    const float4 gb = ((const float4*)gt_boxes)[b*GT + tid];
    gx0[tid]=gb.x; gy0[tid]=gb.y; gx1[tid]=gb.z; gy1[tid]=gb.w;
    ga[tid] = (gb.z-gb.x)*(gb.w-gb.y);
  }
  __syncthreads();
  float bv[GT]; int bi[GT];
  #pragma unroll
  for (int g=0; g<GT; ++g){ bv[g] = -1.0f; bi[g] = 0x7fffffff; }
  for (int p = tid; p < P; p += BPT){          // ascending p per thread
    const float4 pr = ((const float4*)priors)[p];
    const float px0 = pr.x - pr.z*0.5f, py0 = pr.y - pr.w*0.5f;
    const float px1 = pr.x + pr.z*0.5f, py1 = pr.y + pr.w*0.5f;
    const float pa = (px1-px0)*(py1-py0);
    #pragma unroll
    for (int g=0; g<GT; ++g){
      const float w = fmaxf(fminf(gx1[g],px1) - fmaxf(gx0[g],px0), 0.0f);
      const float h = fmaxf(fminf(gy1[g],py1) - fmaxf(gy0[g],py0), 0.0f);
      const float inter = w*h;
      const float iou = inter / (ga[g] + pa - inter);
      if (iou > bv[g]){ bv[g] = iou; bi[g] = p; }   // first-max over p
    }
  }
  #pragma unroll
  for (int g=0; g<GT; ++g){
    float v = bv[g]; int i = bi[g];
    for (int off=32; off>0; off>>=1){
      const float ov = __shfl_down(v, off);
      const int   oi = __shfl_down(i, off);
      if (ov > v || (ov == v && oi < i)){ v = ov; i = oi; } // smaller p on tie
    }
    if (lane == 0){ redv[wave*GT+g] = v; redi[wave*GT+g] = i; }
  }
  __syncthreads();
  if (tid < GT){
    float v = redv[tid]; int i = redi[tid];
    for (int w=1; w<16; ++w){
      const float ov = redv[w*GT+tid]; const int oi = redi[w*GT+tid];
      if (ov > v || (ov == v && oi < i)){ v = ov; i = oi; }
    }
    best[b*GT + tid] = i;
  }
}

// Kernel 2: fused assign + barrier-free pipelined LSE. Each wave owns a
// private 16-row LDS slice -> NO __syncthreads; waves self-pipeline
// (prefetch next logits slice into registers while computing current).
// The q==0 lane of each row-quad additionally performs the per-prior
// assignment inline (16-GT IoU first-max, best-prior last-wins override,
// label, encode + SmoothL1), replicating assign2's exact serial semantics.
// Eliminates the labels/mvv/mmatch workspace round trip and two launches.
__global__ __launch_bounds__(TPB) void fused_lse(
    const float* __restrict__ priors,     // (P,4) xywh
    const float* __restrict__ gt_boxes,   // (B,GT,4) xyxy
    const int*   __restrict__ gt_labels,  // (B,GT)
    const float* __restrict__ box_reg,    // (B,P,4)
    const int*   __restrict__ best,       // (B,GT)
    const float* __restrict__ logits,     // (B*P, 81)
    float* __restrict__ bg,               // (B*P)
    float* __restrict__ ce_pos,           // (B)
    float* __restrict__ sl1_sum,          // (B)
    int*   __restrict__ num_pos,          // (B)
    int P, int NT)                        // NT = B*P/TROWS = 8732 exact
{
  __shared__ float s[TROWS*NCLS];         // 4 waves * 324 float4 = 20736 B
  const int tid = threadIdx.x;
  const int wave = tid >> 6, lane = tid & 63;
  const int rl = lane >> 2, q = lane & 3;
  const int c0 = q ? (1+20*q) : 0;        // [0,21) [21,41) [41,61) [61,81)
  const int c1 = 21 + 20*q;
  const int G = gridDim.x;
  int t = blockIdx.x;
  if (t >= NT) return;

  float4 r0,r1,r2,r3,r4,r5;
  {
    const float4* src = (const float4*)logits + (long long)t*TF4 + wave*WF4;
    r0 = src[lane]; r1 = src[lane+64]; r2 = src[lane+128];
    r3 = src[lane+192]; r4 = src[lane+256];
    if (lane < 4) r5 = src[lane+320];
  }
  float4* sd = (float4*)(s) + wave*WF4;
  const float* x = s + wave*(WF4*4) + rl*NCLS;
  for (; t < NT; t += G){
    sd[lane] = r0; sd[lane+64] = r1; sd[lane+128] = r2;
    sd[lane+192] = r3; sd[lane+256] = r4;
    if (lane < 4) sd[lane+320] = r5;
    const int tn = t + G;
    if (tn < NT){                         // prefetch next slice (stays in flight)
      const float4* src = (const float4*)logits + (long long)tn*TF4 + wave*WF4;
      r0 = src[lane]; r1 = src[lane+64]; r2 = src[lane+128];
      r3 = src[lane+192]; r4 = src[lane+256];
      if (lane < 4) r5 = src[lane+320];
    }

    // ---- inline assignment (q==0 lane of each row) ----
    const int row = t*TROWS + wave*16 + rl;
    const int b = row / P;
    const int p = row - b*P;
    int lab = 0;
    if (q == 0){
      const float4 pr = ((const float4*)priors)[p];
      const float px0 = pr.x - pr.z*0.5f, py0 = pr.y - pr.w*0.5f;
      const float px1 = pr.x + pr.z*0.5f, py1 = pr.y + pr.w*0.5f;
      const float pa = (px1-px0)*(py1-py0);
      const float4* gtb4 = (const float4*)gt_boxes + b*GT;
      float mv = -1.0f; int mi = 0;
      #pragma unroll
      for (int g=0; g<GT; ++g){           // same addr for all 16 q0 lanes: broadcast, L1-hot
        const float4 gb = gtb4[g];
        const float w = fmaxf(fminf(gb.z,px1) - fmaxf(gb.x,px0), 0.0f);
        const float h = fmaxf(fminf(gb.w,py1) - fmaxf(gb.y,py0), 0.0f);
        const float inter = w*h;
        const float garea = (gb.z-gb.x)*(gb.w-gb.y);
        const float iou = inter / (garea + pa - inter);
        if (iou > mv){ mv = iou; mi = g; }          // first-max over g
      }
      const int* bpp = best + b*GT;
      #pragma unroll
      for (int g2=0; g2<GT; ++g2){
        if (bpp[g2] == p){ mv = 2.0f; mi = g2; }    // last g wins
      }
      if (mv >= 0.5f){
        lab = gt_labels[b*GT + mi];
        const float4 gb = gtb4[mi];
        const float ctrx = (gb.x+gb.z)*0.5f, ctry = (gb.y+gb.w)*0.5f;
        const float wx = gb.z-gb.x, wy = gb.w-gb.y;
        const float tx = (ctrx - pr.x) / (0.1f*pr.z);
        const float ty = (ctry - pr.y) / (0.1f*pr.w);
        const float tw = __logf(wx/pr.z) / 0.2f;
        const float th = __logf(wy/pr.w) / 0.2f;
        const float4 br = ((const float4*)box_reg)[(long long)row];
        const float s1 = smoothl1(br.x - tx) + smoothl1(br.y - ty)
                       + smoothl1(br.z - tw) + smoothl1(br.w - th);
        atomicAdd(&sl1_sum[b], s1);                 // fire-and-forget, sparse
        atomicAdd(&num_pos[b], 1);
      }
    }

    // ---- LSE over 81 classes (quad-parallel) ----
    float sum = 0.0f;
    for (int c = c0; c < c1; ++c) sum += __expf(x[c]);
    sum += __shfl_xor(sum, 1);
    sum += __shfl_xor(sum, 2);
    if (q == 0){
      const float lse = __logf(sum);
      float bgv;
      if (lab > 0){
        atomicAdd(&ce_pos[b], lse - x[lab]);        // LDS gather, no vm wait
        bgv = 0.0f;
      } else {
        bgv = fmaxf(lse - x[0], 0.0f);              // clamp: radix needs >=0
      }
      bg[row] = bgv;
    }
  }
}

// Kernel 3: per-batch top-(3*num_pos) sum. Count-only 8-bit radix select
// (16 replicated histograms, stride 257 so replicas of a bin land in
// DIFFERENT banks), then one final pass sums values strictly above the
// threshold; ties contribute krem * threshold. Fused final /N reduce.
__global__ __launch_bounds__(TPB) void topk_kernel(
    const float* __restrict__ bg,
    const int*   __restrict__ num_pos,
    const float* __restrict__ sl1_sum,
    const float* __restrict__ ce_pos,
    float* __restrict__ out,
    int P, int B)
{
  const int b = blockIdx.x;
  const int tid = threadIdx.x;
  const int wave = tid >> 6, lane = tid & 63;
  const int rep = tid & 15;
  __shared__ float sv[MAXP];
  __shared__ unsigned cntR[16][257];    // padded: bank = (rep*257+bin)%32
  __shared__ unsigned s_wc[4];
  __shared__ float    s_wf[4];
  __shared__ unsigned s_prefix;
  __shared__ int s_krem, s_chosen, s_newk;

  {
    const float4* srcp = (const float4*)(bg + (long long)b * P);
    float4* dst = (float4*)sv;
    for (int j = tid; j < P/4; j += TPB) dst[j] = srcp[j];
  }
  if (tid == 0){
    const int k = 3*num_pos[b];
    s_krem = k < P ? k : P-1;
    s_prefix = 0u;
  }
  __syncthreads();

  for (int level=0; level<4; ++level){
    const int shift = 24 - 8*level;
    for (int i = tid; i < 16*257; i += TPB) ((unsigned*)cntR)[i] = 0u;
    __syncthreads();
    const unsigned pref = s_prefix;
    const int k = s_krem;
    for (int j = tid; j < P/4; j += TPB){
      const float4 f4 = ((const float4*)sv)[j];
      #pragma unroll
      for (int e=0; e<4; ++e){
        const unsigned key = __float_as_uint((&f4.x)[e]);
        const bool ok = (level == 0) || ((key >> (shift+8)) == pref);
        if (ok) atomicAdd(&cntR[rep][(key >> shift) & 255u], 1u);
      }
    }
    __syncthreads();
    const int rb = 255 - tid;
    unsigned c = 0;
    #pragma unroll
    for (int r=0; r<16; ++r) c += cntR[r][rb];
    unsigned cv = c;
    #pragma unroll
    for (int off=1; off<64; off<<=1){
      const unsigned oc = __shfl_up(cv, off);
      if (lane >= off) cv += oc;
    }
    if (lane == 63) s_wc[wave] = cv;
    __syncthreads();
    unsigned addc = 0;
    for (int w=0; w<4; ++w) if (w < wave) addc += s_wc[w];
    const unsigned S = cv - c + addc;   // count in bins > rb (matching prefix)
    if ((int)S <= k && k < (int)(S + c)){
      s_chosen = rb; s_newk = k - (int)S;      // exactly one thread
    }
    __syncthreads();
    if (tid == 0){
      s_krem = s_newk;
      s_prefix = (pref << 8) | (unsigned)s_chosen;
    }
    __syncthreads();
  }
  // final pass: sum of values strictly above threshold
  const unsigned T = s_prefix;
  float acc = 0.0f;
  for (int j = tid; j < P/4; j += TPB){
    const float4 f4 = ((const float4*)sv)[j];
    #pragma unroll
    for (int e=0; e<4; ++e){
      const float f = (&f4.x)[e];
      if (__float_as_uint(f) > T) acc += f;
    }
  }
  for (int off=32; off>0; off>>=1) acc += __shfl_down(acc, off);
  if (lane == 0) s_wf[wave] = acc;
  __syncthreads();
  if (tid < 64){                        // wave 0: N = sum(num_pos), /N shares
    float n = 0.0f;
    for (int i = tid; i < B; i += 64) n += (float)num_pos[i];
    for (int off=32; off>0; off>>=1) n += __shfl_down(n, off);
    if (tid == 0){
      const float N = n;
      const float cls = s_wf[0]+s_wf[1]+s_wf[2]+s_wf[3]
                      + (float)s_krem * __uint_as_float(T);
      atomicAdd(&out[0], sl1_sum[b] / N);
      atomicAdd(&out[1], (ce_pos[b] + cls) / N);
    }
  }
}

extern "C" void kernel_launch(void* const* d_in, const int* in_sizes, int n_in,
                              void* d_out, int out_size, void* d_ws, size_t ws_size,
                              hipStream_t stream) {
  const float* priors = (const float*)d_in[0];
  const float* logits = (const float*)d_in[1];
  const float* boxreg = (const float*)d_in[2];
  const float* gtb    = (const float*)d_in[3];
  const int*   gtl    = (const int*)d_in[4];
  const int P = in_sizes[0] / 4;          // 8732
  const int B = in_sizes[4] / GT;         // 64
  const long long BP = (long long)B * P;

  char* ws = (char*)d_ws;
  float* bgv  = (float*)ws;                             // BP float
  int*   best = (int*)(ws + BP*4);                      // B*GT int
  float* sl1_s= (float*)(ws + BP*4 + 4096);
  int*   npos = (int*)  (ws + BP*4 + 4352);
  float* cep  = (float*)(ws + BP*4 + 4608);

  bestprior<<<B, BPT, 0, stream>>>(priors, gtb, best, cep, sl1_s, npos,
                                   (float*)d_out, P);
  const int NT = (int)(BP / TROWS);       // 8732 exact
  const int G = 1792;                     // 7 blocks/CU (20.7 KB LDS)
  fused_lse<<<G, TPB, 0, stream>>>(priors, gtb, gtl, boxreg, best, logits,
                                   bgv, cep, sl1_s, npos, P, NT);
  topk_kernel<<<B, TPB, 0, stream>>>(bgv, npos, sl1_s, cep, (float*)d_out, P, B);
}